// Round 23
// baseline (703.407 us; speedup 1.0000x reference)
//
#include <hip/hip_runtime.h>
#include <math.h>

#define N_NODES 100000
#define N_EDGES 800000
#define NPAD    100096   // 782 * 128
#define FDIM 256
#define HEADS 8
#define CDIM 32
#define OUTF 128

#define SCAN_BLOCK 256
#define SCAN_NBLK ((N_NODES + SCAN_BLOCK - 1) / SCAN_BLOCK)   // 391

typedef _Float16 f16x2 __attribute__((ext_vector_type(2)));
typedef _Float16 f16x8 __attribute__((ext_vector_type(8)));
typedef float  f32x4 __attribute__((ext_vector_type(4)));
typedef unsigned short u16;

__device__ __forceinline__ u16 f2h(float f) {
    union { _Float16 h; u16 u; } c;
    c.h = (_Float16)f;
    return c.u;
}
__device__ __forceinline__ float h2f(u16 u) {
    union { u16 u; _Float16 h; } c;
    c.u = u;
    return (float)c.h;
}
__device__ __forceinline__ f16x2 u2h2(unsigned u) {
    return __builtin_bit_cast(f16x2, u);
}
__device__ __forceinline__ unsigned h2u2(f16x2 h) {
    return __builtin_bit_cast(unsigned, h);
}

__device__ __forceinline__ void gload_lds16(const void* g, void* l) {
    __builtin_amdgcn_global_load_lds((const __attribute__((address_space(1))) void*)g,
                                     (__attribute__((address_space(3))) void*)l, 16, 0, 0);
}

// ---------------- cast f32 -> fp16 (pad region zeroed) ----------------
__global__ void cast_half(const float* __restrict__ src, int n_valid4, int n_pad4,
                          u16* __restrict__ dst) {
    int i = blockIdx.x * blockDim.x + threadIdx.x;
    int stride = gridDim.x * blockDim.x;
    for (; i < n_pad4; i += stride) {
        f32x4 v = {0.f, 0.f, 0.f, 0.f};
        if (i < n_valid4) v = ((const f32x4*)src)[i];
        ((ushort4*)dst)[i] = make_ushort4(f2h(v[0]), f2h(v[1]), f2h(v[2]), f2h(v[3]));
    }
}

// ---------------- W prep: transpose + concat, fp16 ----------------
__global__ void prep_w_layer(const float* __restrict__ Wl, const float* __restrict__ Wr,
                             u16* __restrict__ Wt) {
    int idx = blockIdx.x * blockDim.x + threadIdx.x;
    if (idx >= 512 * 256) return;
    int n = idx >> 8, k = idx & 255;
    float w = (n < 256) ? Wl[k * 256 + n] : Wr[k * 256 + (n - 256)];
    Wt[idx] = f2h(w);
}

__global__ void prep_w_fc(const float* __restrict__ Wfc, u16* __restrict__ Wt) {
    int idx = blockIdx.x * blockDim.x + threadIdx.x;
    if (idx >= 128 * 256) return;
    int n = idx >> 8, k = idx & 255;
    Wt[idx] = f2h(Wfc[k * 128 + n]);
}

// ---------------- fp16 MFMA GEMM, 2-phase dbuf LDS, 8 waves/block ----------------
template <bool HOUT, int NS, bool L2N>
__global__ __launch_bounds__(512) void gemm_h(
        const u16* __restrict__ A, const u16* __restrict__ Wt,
        const float* __restrict__ bias0, const float* __restrict__ bias1,
        void* __restrict__ C0v, void* __restrict__ C1v, int ldc, int M) {
    __shared__ __align__(16) u16 lA[2][128 * 64];
    __shared__ __align__(16) u16 lB[2][128 * 64];
    __shared__ float rssq[128];

    int tid = threadIdx.x;
    int wid = tid >> 6, lane = tid & 63;
    int wm = wid >> 1, wn = wid & 1;      // 4m x 2n wave grid
    int lr = lane & 15, lk = lane >> 4;

    // bijective XCD swizzle: consecutive swz ids stay on one XCD
    int orig = blockIdx.x;
    int nwg = gridDim.x;
    int q = nwg >> 3, r = nwg & 7;
    int xcd = orig & 7, loc = orig >> 3;
    int swz = (xcd < r) ? (xcd * (q + 1) + loc) : (r * (q + 1) + (xcd - r) * q + loc);
    int m0 = (swz / NS) * 128;
    int n0 = (swz % NS) * 128;

    auto stage = [&](int buf, int k0) {
#pragma unroll
        for (int i = 0; i < 2; i++) {
            int t = i * 512 + tid;
            int row = t >> 3;
            int ch = (t & 7) ^ (row & 7);
            gload_lds16(A + (size_t)(m0 + row) * 256 + k0 + ch * 8,
                        (char*)lA[buf] + i * 8192 + wid * 1024);
        }
#pragma unroll
        for (int i = 0; i < 2; i++) {
            int t = i * 512 + tid;
            int row = t >> 3;
            int ch = (t & 7) ^ (row & 7);
            gload_lds16(Wt + (size_t)(n0 + row) * 256 + k0 + ch * 8,
                        (char*)lB[buf] + i * 8192 + wid * 1024);
        }
    };

    f32x4 acc[2][4] = {};

    stage(0, 0);
    __syncthreads();

#pragma unroll 1
    for (int ks = 0; ks < 4; ks++) {
        int cur = ks & 1;
        if (ks < 3) stage(cur ^ 1, (ks + 1) * 64);

#pragma unroll
        for (int kk = 0; kk < 2; kk++) {
            f16x8 af[2], bf[4];
#pragma unroll
            for (int mr = 0; mr < 2; mr++) {
                int rr = wm * 32 + mr * 16 + lr;
                int qq = (kk * 4 + lk) ^ (rr & 7);
                af[mr] = *(const f16x8*)&lA[cur][rr * 64 + qq * 8];
            }
#pragma unroll
            for (int nr = 0; nr < 4; nr++) {
                int rr = wn * 64 + nr * 16 + lr;
                int qq = (kk * 4 + lk) ^ (rr & 7);
                bf[nr] = *(const f16x8*)&lB[cur][rr * 64 + qq * 8];
            }
#pragma unroll
            for (int mr = 0; mr < 2; mr++)
#pragma unroll
                for (int nr = 0; nr < 4; nr++)
                    acc[mr][nr] = __builtin_amdgcn_mfma_f32_16x16x32_f16(
                        af[mr], bf[nr], acc[mr][nr], 0, 0, 0);
        }
        __syncthreads();
    }

    // add bias in place
#pragma unroll
    for (int mr = 0; mr < 2; mr++)
#pragma unroll
        for (int nr = 0; nr < 4; nr++) {
            int col = n0 + wn * 64 + nr * 16 + lr;
            float b = (col < 256) ? bias0[col] : bias1[col - 256];
#pragma unroll
            for (int j = 0; j < 4; j++) acc[mr][nr][j] += b;
        }

    if constexpr (L2N) {
        if (tid < 128) rssq[tid] = 0.f;
        __syncthreads();
#pragma unroll
        for (int mr = 0; mr < 2; mr++)
#pragma unroll
            for (int j = 0; j < 4; j++) {
                int rl = wm * 32 + mr * 16 + lk * 4 + j;
                float s = 0.f;
#pragma unroll
                for (int nr = 0; nr < 4; nr++) s += acc[mr][nr][j] * acc[mr][nr][j];
                atomicAdd(&rssq[rl], s);
            }
        __syncthreads();
#pragma unroll
        for (int mr = 0; mr < 2; mr++)
#pragma unroll
            for (int j = 0; j < 4; j++) {
                int rl = wm * 32 + mr * 16 + lk * 4 + j;
                int row = m0 + rl;
                if (row < M) {
                    float inv = 1.f / fmaxf(sqrtf(rssq[rl]), 1e-12f);
#pragma unroll
                    for (int nr = 0; nr < 4; nr++) {
                        int col = n0 + wn * 64 + nr * 16 + lr;
                        ((float*)C0v)[(size_t)row * ldc + col] = acc[mr][nr][j] * inv;
                    }
                }
            }
    } else {
#pragma unroll
        for (int mr = 0; mr < 2; mr++)
#pragma unroll
            for (int nr = 0; nr < 4; nr++) {
                int col = n0 + wn * 64 + nr * 16 + lr;
                void* Cp; int c;
                if (col < 256) { Cp = C0v; c = col; }
                else           { Cp = C1v; c = col - 256; }
#pragma unroll
                for (int j = 0; j < 4; j++) {
                    int row = m0 + wm * 32 + mr * 16 + lk * 4 + j;
                    if (row < M) {
                        float v = acc[mr][nr][j];
                        if constexpr (HOUT)
                            ((u16*)Cp)[(size_t)row * ldc + c] = f2h(v);
                        else
                            ((float*)Cp)[(size_t)row * ldc + c] = v;
                    }
                }
            }
    }
}

// ---------------- CSR build ----------------
__global__ void count_deg(const int* __restrict__ dstA, int* __restrict__ deg) {
    int i = blockIdx.x * blockDim.x + threadIdx.x;
    int stride = gridDim.x * blockDim.x;
    for (; i < N_EDGES; i += stride) atomicAdd(&deg[dstA[i]], 1);
}

__global__ void scan_phase1(const int* __restrict__ deg, int* __restrict__ blocksum) {
    __shared__ int sdata[SCAN_BLOCK];
    int i = blockIdx.x * SCAN_BLOCK + threadIdx.x;
    sdata[threadIdx.x] = (i < N_NODES) ? deg[i] : 0;
    __syncthreads();
    for (int off = SCAN_BLOCK / 2; off > 0; off >>= 1) {
        if (threadIdx.x < off) sdata[threadIdx.x] += sdata[threadIdx.x + off];
        __syncthreads();
    }
    if (threadIdx.x == 0) blocksum[blockIdx.x] = sdata[0];
}

__global__ void scan_phase2(int* __restrict__ blocksum) {
    __shared__ int part[512];
    int t = threadIdx.x;
    int v = (t < SCAN_NBLK) ? blocksum[t] : 0;
    part[t] = v;
    __syncthreads();
    for (int off = 1; off < 512; off <<= 1) {
        int u = 0;
        if (t >= off) u = part[t - off];
        __syncthreads();
        if (t >= off) part[t] += u;
        __syncthreads();
    }
    if (t < SCAN_NBLK) blocksum[t] = part[t] - v;   // exclusive
}

__global__ void scan_phase3(const int* __restrict__ deg, const int* __restrict__ blockoff,
                            int* __restrict__ rowstart, int* __restrict__ cursor) {
    __shared__ int part[SCAN_BLOCK];
    int t = threadIdx.x;
    int i = blockIdx.x * SCAN_BLOCK + t;
    int v = (i < N_NODES) ? deg[i] : 0;
    part[t] = v;
    __syncthreads();
    for (int off = 1; off < SCAN_BLOCK; off <<= 1) {
        int u = 0;
        if (t >= off) u = part[t - off];
        __syncthreads();
        if (t >= off) part[t] += u;
        __syncthreads();
    }
    if (i < N_NODES) {
        int excl = blockoff[blockIdx.x] + part[t] - v;
        rowstart[i] = excl;
        cursor[i] = excl;
        if (i == N_NODES - 1) rowstart[N_NODES] = blockoff[blockIdx.x] + part[t];
    }
}

__global__ void fill_csr(const int* __restrict__ srcA, const int* __restrict__ dstA,
                         int* __restrict__ cursor, int* __restrict__ csr_src) {
    int i = blockIdx.x * blockDim.x + threadIdx.x;
    int stride = gridDim.x * blockDim.x;
    for (; i < N_EDGES; i += stride) {
        int pos = atomicAdd(&cursor[dstA[i]], 1);
        csr_src[pos] = srcA[i];
    }
}

// ---------------- Fused GATv2 edge phase (one wave per destination) ----------------
// Two 32-lane halves; each half processes FOUR independent edges per iteration
// (offsets 8t+up+2k, k=0..3): 4 logit chains interleave; 8 gather streams in flight.
__global__ void gat_fused(const u16* __restrict__ xl, const u16* __restrict__ xr,
                          const int* __restrict__ rowstart, const int* __restrict__ csr_src,
                          const float* __restrict__ att, u16* __restrict__ out) {
    int wid = (blockIdx.x * blockDim.x + threadIdx.x) >> 6;
    int lane = threadIdx.x & 63;
    if (wid >= N_NODES) return;
    int hl = lane & 31;   // lane within half
    int up = lane >> 5;   // edge slot parity
    int c0 = hl * 8;      // 8 columns per lane

    uint4 xru = *(const uint4*)(xr + (size_t)wid * FDIM + c0);
    f16x2 xr0 = u2h2(xru.x), xr1 = u2h2(xru.y), xr2 = u2h2(xru.z), xr3 = u2h2(xru.w);
    f32x4 av0 = *(const f32x4*)(att + c0);
    f32x4 av1 = *(const f32x4*)(att + c0 + 4);
    f16x2 a0 = {(_Float16)av0[0], (_Float16)av0[1]};
    f16x2 a1 = {(_Float16)av0[2], (_Float16)av0[3]};
    f16x2 a2 = {(_Float16)av1[0], (_Float16)av1[1]};
    f16x2 a3 = {(_Float16)av1[2], (_Float16)av1[3]};
    const f16x2 k02 = {(_Float16)0.2f, (_Float16)0.2f};

    f16x2 acc0 = {(_Float16)0.f, (_Float16)0.f};
    f16x2 acc1 = acc0, acc2 = acc0, acc3 = acc0;
    float den = 0.f;

    int jb = rowstart[wid], je = rowstart[wid + 1];
    if (jb < je) {
        int jlast = je - 1;
        int D = je - jb;
        int nsteps = (D + 7) >> 3;   // each iter: this half covers 8t+up+{0,2,4,6}
        auto clamp = [&](int e) { return e > jlast ? jlast : e; };

        uint4 u[4], n[4];
#pragma unroll
        for (int k = 0; k < 4; k++)
            u[k] = *(const uint4*)(xl + (size_t)csr_src[clamp(jb + up + 2 * k)] * FDIM + c0);

        for (int t = 0; t < nsteps; ++t) {
            int base = jb + 8 * t + up;
#pragma unroll
            for (int k = 0; k < 4; k++)
                n[k] = *(const uint4*)(xl + (size_t)csr_src[clamp(base + 8 + 2 * k)] * FDIM + c0);

#pragma unroll
            for (int k = 0; k < 4; k++) {
                f16x2 x0 = u2h2(u[k].x), x1 = u2h2(u[k].y);
                f16x2 x2 = u2h2(u[k].z), x3 = u2h2(u[k].w);
                f16x2 v0 = x0 + xr0, v1 = x1 + xr1, v2 = x2 + xr2, v3 = x3 + xr3;
                f16x2 t0 = __builtin_elementwise_max(v0, v0 * k02);
                f16x2 t1 = __builtin_elementwise_max(v1, v1 * k02);
                f16x2 t2 = __builtin_elementwise_max(v2, v2 * k02);
                f16x2 t3 = __builtin_elementwise_max(v3, v3 * k02);
                float s = __builtin_amdgcn_fdot2(t0, a0, 0.f, false);
                s = __builtin_amdgcn_fdot2(t1, a1, s, false);
                s = __builtin_amdgcn_fdot2(t2, a2, s, false);
                s = __builtin_amdgcn_fdot2(t3, a3, s, false);
                s += __shfl_xor(s, 1);
                s += __shfl_xor(s, 2);
                float e = (base + 2 * k <= jlast) ? __expf(s) : 0.f;
                den += e;
                _Float16 eh = (_Float16)e;
                f16x2 ev = {eh, eh};
                acc0 += ev * x0;
                acc1 += ev * x1;
                acc2 += ev * x2;
                acc3 += ev * x3;
            }
#pragma unroll
            for (int k = 0; k < 4; k++) u[k] = n[k];
        }
    }
    // merge the two halves (same columns, disjoint edge sets)
    den += __shfl_xor(den, 32);
    acc0 += u2h2(__shfl_xor((int)h2u2(acc0), 32));
    acc1 += u2h2(__shfl_xor((int)h2u2(acc1), 32));
    acc2 += u2h2(__shfl_xor((int)h2u2(acc2), 32));
    acc3 += u2h2(__shfl_xor((int)h2u2(acc3), 32));

    if (up == 0) {
        float invf = 1.f / (den + 1e-16f);
        u16 h[8];
        h[0] = f2h((float)acc0[0] * invf); h[1] = f2h((float)acc0[1] * invf);
        h[2] = f2h((float)acc1[0] * invf); h[3] = f2h((float)acc1[1] * invf);
        h[4] = f2h((float)acc2[0] * invf); h[5] = f2h((float)acc2[1] * invf);
        h[6] = f2h((float)acc3[0] * invf); h[7] = f2h((float)acc3[1] * invf);
        *(uint4*)(out + (size_t)wid * FDIM + c0) = *(const uint4*)h;
    }
}

// ---------------- BatchNorm stats: vectorized ushort4 reads ----------------
// Thread (tid&63) owns cols 4c..4c+3; 4 row-slots per block; LDS reduce; 512 atomics.
__global__ void bn_stats_h(const u16* __restrict__ X, float* __restrict__ sum,
                           float* __restrict__ sumsq, int nrows) {
    __shared__ float red[4][64][8];
    int tid = threadIdx.x;
    int cg = tid & 63;
    int rg = tid >> 6;
    float s0 = 0.f, s1 = 0.f, s2 = 0.f, s3 = 0.f;
    float q0 = 0.f, q1 = 0.f, q2 = 0.f, q3 = 0.f;
    for (int r = blockIdx.x * 4 + rg; r < nrows; r += gridDim.x * 4) {
        ushort4 v = *(const ushort4*)&X[(size_t)r * FDIM + cg * 4];
        float f0 = h2f(v.x), f1 = h2f(v.y), f2 = h2f(v.z), f3 = h2f(v.w);
        s0 += f0; q0 += f0 * f0;
        s1 += f1; q1 += f1 * f1;
        s2 += f2; q2 += f2 * f2;
        s3 += f3; q3 += f3 * f3;
    }
    red[rg][cg][0] = s0; red[rg][cg][1] = s1; red[rg][cg][2] = s2; red[rg][cg][3] = s3;
    red[rg][cg][4] = q0; red[rg][cg][5] = q1; red[rg][cg][6] = q2; red[rg][cg][7] = q3;
    __syncthreads();
    if (tid < 64) {
#pragma unroll
        for (int i = 0; i < 4; i++) {
            float ts = red[0][tid][i] + red[1][tid][i] + red[2][tid][i] + red[3][tid][i];
            atomicAdd(&sum[tid * 4 + i], ts);
            float tq = red[0][tid][4 + i] + red[1][tid][4 + i] + red[2][tid][4 + i] + red[3][tid][4 + i];
            atomicAdd(&sumsq[tid * 4 + i], tq);
        }
    }
}

__global__ void bn_finalize(const float* __restrict__ sum, const float* __restrict__ sumsq,
                            const float* __restrict__ gamma, const float* __restrict__ beta,
                            float* __restrict__ scale, float* __restrict__ shift) {
    int c = threadIdx.x;
    float mean = sum[c] * (1.f / N_NODES);
    float var = sumsq[c] * (1.f / N_NODES) - mean * mean;
    float sc = gamma[c] * rsqrtf(var + 1e-5f);
    scale[c] = sc;
    shift[c] = beta[c] - mean * sc;
}

// BN + ELU fused: fp16 in, fp16 out (pad rows zeroed)
__global__ void bn_elu_h(const u16* __restrict__ X, const float* __restrict__ scale,
                         const float* __restrict__ shift, u16* __restrict__ dst) {
    int i = blockIdx.x * blockDim.x + threadIdx.x;   // ushort4 units
    int stride = gridDim.x * blockDim.x;
    const int n_valid4 = N_NODES * FDIM / 4;
    const int n_pad4 = NPAD * FDIM / 4;
    for (; i < n_pad4; i += stride) {
        u16 h[4] = {0, 0, 0, 0};
        if (i < n_valid4) {
            ushort4 v = ((const ushort4*)X)[i];
            int c0 = (i * 4) & (FDIM - 1);
            float f0 = h2f(v.x) * scale[c0 + 0] + shift[c0 + 0];
            float f1 = h2f(v.y) * scale[c0 + 1] + shift[c0 + 1];
            float f2 = h2f(v.z) * scale[c0 + 2] + shift[c0 + 2];
            float f3 = h2f(v.w) * scale[c0 + 3] + shift[c0 + 3];
            f0 = f0 > 0.f ? f0 : expf(f0) - 1.f;
            f1 = f1 > 0.f ? f1 : expf(f1) - 1.f;
            f2 = f2 > 0.f ? f2 : expf(f2) - 1.f;
            f3 = f3 > 0.f ? f3 : expf(f3) - 1.f;
            h[0] = f2h(f0); h[1] = f2h(f1); h[2] = f2h(f2); h[3] = f2h(f3);
        }
        ((ushort4*)dst)[i] = make_ushort4(h[0], h[1], h[2], h[3]);
    }
}

extern "C" void kernel_launch(void* const* d_in, const int* in_sizes, int n_in,
                              void* d_out, int out_size, void* d_ws, size_t ws_size,
                              hipStream_t stream) {
    const float* x     = (const float*)d_in[0];
    const int*   ei    = (const int*)d_in[1];
    const float* Wl1   = (const float*)d_in[2];
    const float* bl1   = (const float*)d_in[3];
    const float* Wr1   = (const float*)d_in[4];
    const float* br1   = (const float*)d_in[5];
    const float* att1  = (const float*)d_in[6];
    // d_in[7] = bias1 : cancels exactly inside batchnorm -> skipped
    const float* gamma1 = (const float*)d_in[8];
    const float* beta1  = (const float*)d_in[9];
    const float* Wl2   = (const float*)d_in[10];
    const float* bl2   = (const float*)d_in[11];
    const float* Wr2   = (const float*)d_in[12];
    const float* br2   = (const float*)d_in[13];
    const float* att2  = (const float*)d_in[14];
    // d_in[15] = bias2 : cancels inside batchnorm -> skipped
    const float* gamma2 = (const float*)d_in[16];
    const float* beta2  = (const float*)d_in[17];
    const float* Wfc   = (const float*)d_in[18];
    const float* bfc   = (const float*)d_in[19];

    const int* srcA = ei;
    const int* dstA = ei + N_EDGES;

    const size_t REG = (size_t)NPAD * FDIM * 4;
    char* p = (char*)d_ws;
    char* R0 = p;            p += REG;
    char* R1 = p;            p += REG;
    char* R2 = p;            p += REG;
    u16* WTH   = (u16*)p;              p += 512 * 256 * 2;
    float* SUM = (float*)p;            p += FDIM * 4;
    float* SQ  = (float*)p;            p += FDIM * 4;
    float* SC  = (float*)p;            p += FDIM * 4;
    float* SH  = (float*)p;            p += FDIM * 4;
    int* DEG      = (int*)p;           p += (size_t)N_NODES * 4;
    int* ROWSTART = (int*)p;           p += (size_t)(N_NODES + 1) * 4;
    int* CURSOR   = (int*)p;           p += (size_t)N_NODES * 4;
    int* CSR      = (int*)p;           p += (size_t)N_EDGES * 4;
    int* BLKSUM   = (int*)p;           p += (size_t)SCAN_NBLK * 4;

    const int gat_grid = (N_NODES + 3) / 4;   // one wave per node
    const int gemm_grid_layer = (NPAD / 128) * 4;  // 3128, 1D (swizzled in-kernel)
    const int gemm_grid_fc = NPAD / 128;           // 782

    // ---------------- CSR build ----------------
    hipMemsetAsync(DEG, 0, (size_t)N_NODES * sizeof(int), stream);
    count_deg<<<2048, 256, 0, stream>>>(dstA, DEG);
    scan_phase1<<<SCAN_NBLK, SCAN_BLOCK, 0, stream>>>(DEG, BLKSUM);
    scan_phase2<<<1, 512, 0, stream>>>(BLKSUM);
    scan_phase3<<<SCAN_NBLK, SCAN_BLOCK, 0, stream>>>(DEG, BLKSUM, ROWSTART, CURSOR);
    fill_csr<<<2048, 256, 0, stream>>>(srcA, dstA, CURSOR, CSR);

    // ---------------- Layer 1 ----------------
    // A(fp16) @ R0 ; gemm -> xl(fp16) @ R1, xr(fp16) @ R2 ; gat -> O(fp16) @ R0
    cast_half<<<4096, 256, 0, stream>>>(x, N_NODES * FDIM / 4, NPAD * FDIM / 4, (u16*)R0);
    prep_w_layer<<<512, 256, 0, stream>>>(Wl1, Wr1, WTH);
    gemm_h<true, 4, false><<<gemm_grid_layer, 512, 0, stream>>>((u16*)R0, WTH, bl1, br1, R1, R2, 256, N_NODES);
    gat_fused<<<gat_grid, 256, 0, stream>>>((u16*)R1, (u16*)R2, ROWSTART, CSR, att1, (u16*)R0);

    hipMemsetAsync(SUM, 0, 2 * FDIM * sizeof(float), stream);
    bn_stats_h<<<1024, 256, 0, stream>>>((u16*)R0, SUM, SQ, N_NODES);
    bn_finalize<<<1, 256, 0, stream>>>(SUM, SQ, gamma1, beta1, SC, SH);
    bn_elu_h<<<2048, 256, 0, stream>>>((u16*)R0, SC, SH, (u16*)R1);

    // ---------------- Layer 2 ----------------
    prep_w_layer<<<512, 256, 0, stream>>>(Wl2, Wr2, WTH);
    gemm_h<true, 4, false><<<gemm_grid_layer, 512, 0, stream>>>((u16*)R1, WTH, bl2, br2, R2, R0, 256, N_NODES);
    gat_fused<<<gat_grid, 256, 0, stream>>>((u16*)R2, (u16*)R0, ROWSTART, CSR, att2, (u16*)R1);

    hipMemsetAsync(SUM, 0, 2 * FDIM * sizeof(float), stream);
    bn_stats_h<<<1024, 256, 0, stream>>>((u16*)R1, SUM, SQ, N_NODES);
    bn_finalize<<<1, 256, 0, stream>>>(SUM, SQ, gamma2, beta2, SC, SH);
    bn_elu_h<<<2048, 256, 0, stream>>>((u16*)R1, SC, SH, (u16*)R2);

    // ---------------- FC with fused L2 normalize ----------------
    prep_w_fc<<<128, 256, 0, stream>>>(Wfc, WTH);
    gemm_h<false, 1, true><<<gemm_grid_fc, 512, 0, stream>>>((u16*)R2, WTH, bfc, bfc, d_out, d_out, 128, N_NODES);
}

// Round 24
// 560.211 us; speedup vs baseline: 1.2556x; 1.2556x over previous
//
#include <hip/hip_runtime.h>
#include <math.h>

#define N_NODES 100000
#define N_EDGES 800000
#define NPAD    100096   // 782 * 128
#define FDIM 256
#define HEADS 8
#define CDIM 32
#define OUTF 128

#define SCAN_BLOCK 256
#define SCAN_NBLK ((N_NODES + SCAN_BLOCK - 1) / SCAN_BLOCK)   // 391

typedef _Float16 f16x2 __attribute__((ext_vector_type(2)));
typedef _Float16 f16x8 __attribute__((ext_vector_type(8)));
typedef float  f32x4 __attribute__((ext_vector_type(4)));
typedef unsigned short u16;

__device__ __forceinline__ u16 f2h(float f) {
    union { _Float16 h; u16 u; } c;
    c.h = (_Float16)f;
    return c.u;
}
__device__ __forceinline__ float h2f(u16 u) {
    union { u16 u; _Float16 h; } c;
    c.u = u;
    return (float)c.h;
}
__device__ __forceinline__ f16x2 u2h2(unsigned u) {
    return __builtin_bit_cast(f16x2, u);
}
__device__ __forceinline__ unsigned h2u2(f16x2 h) {
    return __builtin_bit_cast(unsigned, h);
}

__device__ __forceinline__ void gload_lds16(const void* g, void* l) {
    __builtin_amdgcn_global_load_lds((const __attribute__((address_space(1))) void*)g,
                                     (__attribute__((address_space(3))) void*)l, 16, 0, 0);
}

// ---------------- cast f32 -> fp16 (pad region zeroed) ----------------
__global__ void cast_half(const float* __restrict__ src, int n_valid4, int n_pad4,
                          u16* __restrict__ dst) {
    int i = blockIdx.x * blockDim.x + threadIdx.x;
    int stride = gridDim.x * blockDim.x;
    for (; i < n_pad4; i += stride) {
        f32x4 v = {0.f, 0.f, 0.f, 0.f};
        if (i < n_valid4) v = ((const f32x4*)src)[i];
        ((ushort4*)dst)[i] = make_ushort4(f2h(v[0]), f2h(v[1]), f2h(v[2]), f2h(v[3]));
    }
}

// ---------------- W prep: transpose + concat, fp16 ----------------
__global__ void prep_w_layer(const float* __restrict__ Wl, const float* __restrict__ Wr,
                             u16* __restrict__ Wt) {
    int idx = blockIdx.x * blockDim.x + threadIdx.x;
    if (idx >= 512 * 256) return;
    int n = idx >> 8, k = idx & 255;
    float w = (n < 256) ? Wl[k * 256 + n] : Wr[k * 256 + (n - 256)];
    Wt[idx] = f2h(w);
}

__global__ void prep_w_fc(const float* __restrict__ Wfc, u16* __restrict__ Wt) {
    int idx = blockIdx.x * blockDim.x + threadIdx.x;
    if (idx >= 128 * 256) return;
    int n = idx >> 8, k = idx & 255;
    Wt[idx] = f2h(Wfc[k * 128 + n]);
}

// ---------------- fp16 MFMA GEMM, 2-phase dbuf LDS, 8 waves/block ----------------
template <bool HOUT, int NS, bool L2N>
__global__ __launch_bounds__(512) void gemm_h(
        const u16* __restrict__ A, const u16* __restrict__ Wt,
        const float* __restrict__ bias0, const float* __restrict__ bias1,
        void* __restrict__ C0v, void* __restrict__ C1v, int ldc, int M) {
    __shared__ __align__(16) u16 lA[2][128 * 64];
    __shared__ __align__(16) u16 lB[2][128 * 64];
    __shared__ float rssq[128];

    int tid = threadIdx.x;
    int wid = tid >> 6, lane = tid & 63;
    int wm = wid >> 1, wn = wid & 1;      // 4m x 2n wave grid
    int lr = lane & 15, lk = lane >> 4;

    // bijective XCD swizzle: consecutive swz ids stay on one XCD
    int orig = blockIdx.x;
    int nwg = gridDim.x;
    int q = nwg >> 3, r = nwg & 7;
    int xcd = orig & 7, loc = orig >> 3;
    int swz = (xcd < r) ? (xcd * (q + 1) + loc) : (r * (q + 1) + (xcd - r) * q + loc);
    int m0 = (swz / NS) * 128;
    int n0 = (swz % NS) * 128;

    auto stage = [&](int buf, int k0) {
#pragma unroll
        for (int i = 0; i < 2; i++) {
            int t = i * 512 + tid;
            int row = t >> 3;
            int ch = (t & 7) ^ (row & 7);
            gload_lds16(A + (size_t)(m0 + row) * 256 + k0 + ch * 8,
                        (char*)lA[buf] + i * 8192 + wid * 1024);
        }
#pragma unroll
        for (int i = 0; i < 2; i++) {
            int t = i * 512 + tid;
            int row = t >> 3;
            int ch = (t & 7) ^ (row & 7);
            gload_lds16(Wt + (size_t)(n0 + row) * 256 + k0 + ch * 8,
                        (char*)lB[buf] + i * 8192 + wid * 1024);
        }
    };

    f32x4 acc[2][4] = {};

    stage(0, 0);
    __syncthreads();

#pragma unroll 1
    for (int ks = 0; ks < 4; ks++) {
        int cur = ks & 1;
        if (ks < 3) stage(cur ^ 1, (ks + 1) * 64);

#pragma unroll
        for (int kk = 0; kk < 2; kk++) {
            f16x8 af[2], bf[4];
#pragma unroll
            for (int mr = 0; mr < 2; mr++) {
                int rr = wm * 32 + mr * 16 + lr;
                int qq = (kk * 4 + lk) ^ (rr & 7);
                af[mr] = *(const f16x8*)&lA[cur][rr * 64 + qq * 8];
            }
#pragma unroll
            for (int nr = 0; nr < 4; nr++) {
                int rr = wn * 64 + nr * 16 + lr;
                int qq = (kk * 4 + lk) ^ (rr & 7);
                bf[nr] = *(const f16x8*)&lB[cur][rr * 64 + qq * 8];
            }
#pragma unroll
            for (int mr = 0; mr < 2; mr++)
#pragma unroll
                for (int nr = 0; nr < 4; nr++)
                    acc[mr][nr] = __builtin_amdgcn_mfma_f32_16x16x32_f16(
                        af[mr], bf[nr], acc[mr][nr], 0, 0, 0);
        }
        __syncthreads();
    }

    // add bias in place
#pragma unroll
    for (int mr = 0; mr < 2; mr++)
#pragma unroll
        for (int nr = 0; nr < 4; nr++) {
            int col = n0 + wn * 64 + nr * 16 + lr;
            float b = (col < 256) ? bias0[col] : bias1[col - 256];
#pragma unroll
            for (int j = 0; j < 4; j++) acc[mr][nr][j] += b;
        }

    if constexpr (L2N) {
        if (tid < 128) rssq[tid] = 0.f;
        __syncthreads();
#pragma unroll
        for (int mr = 0; mr < 2; mr++)
#pragma unroll
            for (int j = 0; j < 4; j++) {
                int rl = wm * 32 + mr * 16 + lk * 4 + j;
                float s = 0.f;
#pragma unroll
                for (int nr = 0; nr < 4; nr++) s += acc[mr][nr][j] * acc[mr][nr][j];
                atomicAdd(&rssq[rl], s);
            }
        __syncthreads();
#pragma unroll
        for (int mr = 0; mr < 2; mr++)
#pragma unroll
            for (int j = 0; j < 4; j++) {
                int rl = wm * 32 + mr * 16 + lk * 4 + j;
                int row = m0 + rl;
                if (row < M) {
                    float inv = 1.f / fmaxf(sqrtf(rssq[rl]), 1e-12f);
#pragma unroll
                    for (int nr = 0; nr < 4; nr++) {
                        int col = n0 + wn * 64 + nr * 16 + lr;
                        ((float*)C0v)[(size_t)row * ldc + col] = acc[mr][nr][j] * inv;
                    }
                }
            }
    } else {
#pragma unroll
        for (int mr = 0; mr < 2; mr++)
#pragma unroll
            for (int nr = 0; nr < 4; nr++) {
                int col = n0 + wn * 64 + nr * 16 + lr;
                void* Cp; int c;
                if (col < 256) { Cp = C0v; c = col; }
                else           { Cp = C1v; c = col - 256; }
#pragma unroll
                for (int j = 0; j < 4; j++) {
                    int row = m0 + wm * 32 + mr * 16 + lk * 4 + j;
                    if (row < M) {
                        float v = acc[mr][nr][j];
                        if constexpr (HOUT)
                            ((u16*)Cp)[(size_t)row * ldc + c] = f2h(v);
                        else
                            ((float*)Cp)[(size_t)row * ldc + c] = v;
                    }
                }
            }
    }
}

// ---------------- CSR build ----------------
__global__ void count_deg(const int* __restrict__ dstA, int* __restrict__ deg) {
    int i = blockIdx.x * blockDim.x + threadIdx.x;
    int stride = gridDim.x * blockDim.x;
    for (; i < N_EDGES; i += stride) atomicAdd(&deg[dstA[i]], 1);
}

__global__ void scan_phase1(const int* __restrict__ deg, int* __restrict__ blocksum) {
    __shared__ int sdata[SCAN_BLOCK];
    int i = blockIdx.x * SCAN_BLOCK + threadIdx.x;
    sdata[threadIdx.x] = (i < N_NODES) ? deg[i] : 0;
    __syncthreads();
    for (int off = SCAN_BLOCK / 2; off > 0; off >>= 1) {
        if (threadIdx.x < off) sdata[threadIdx.x] += sdata[threadIdx.x + off];
        __syncthreads();
    }
    if (threadIdx.x == 0) blocksum[blockIdx.x] = sdata[0];
}

__global__ void scan_phase2(int* __restrict__ blocksum) {
    __shared__ int part[512];
    int t = threadIdx.x;
    int v = (t < SCAN_NBLK) ? blocksum[t] : 0;
    part[t] = v;
    __syncthreads();
    for (int off = 1; off < 512; off <<= 1) {
        int u = 0;
        if (t >= off) u = part[t - off];
        __syncthreads();
        if (t >= off) part[t] += u;
        __syncthreads();
    }
    if (t < SCAN_NBLK) blocksum[t] = part[t] - v;   // exclusive
}

__global__ void scan_phase3(const int* __restrict__ deg, const int* __restrict__ blockoff,
                            int* __restrict__ rowstart, int* __restrict__ cursor) {
    __shared__ int part[SCAN_BLOCK];
    int t = threadIdx.x;
    int i = blockIdx.x * SCAN_BLOCK + t;
    int v = (i < N_NODES) ? deg[i] : 0;
    part[t] = v;
    __syncthreads();
    for (int off = 1; off < SCAN_BLOCK; off <<= 1) {
        int u = 0;
        if (t >= off) u = part[t - off];
        __syncthreads();
        if (t >= off) part[t] += u;
        __syncthreads();
    }
    if (i < N_NODES) {
        int excl = blockoff[blockIdx.x] + part[t] - v;
        rowstart[i] = excl;
        cursor[i] = excl;
        if (i == N_NODES - 1) rowstart[N_NODES] = blockoff[blockIdx.x] + part[t];
    }
}

__global__ void fill_csr(const int* __restrict__ srcA, const int* __restrict__ dstA,
                         int* __restrict__ cursor, int* __restrict__ csr_src) {
    int i = blockIdx.x * blockDim.x + threadIdx.x;
    int stride = gridDim.x * blockDim.x;
    for (; i < N_EDGES; i += stride) {
        int pos = atomicAdd(&cursor[dstA[i]], 1);
        csr_src[pos] = srcA[i];
    }
}

// ---------------- Fused GATv2 edge phase (one wave per destination) ----------------
// Two 32-lane halves; each half processes TWO independent edges per iteration
// (offsets 4t+up and 4t+up+2) so two logit chains interleave in the issue window.
__global__ void gat_fused(const u16* __restrict__ xl, const u16* __restrict__ xr,
                          const int* __restrict__ rowstart, const int* __restrict__ csr_src,
                          const float* __restrict__ att, u16* __restrict__ out) {
    int wid = (blockIdx.x * blockDim.x + threadIdx.x) >> 6;
    int lane = threadIdx.x & 63;
    if (wid >= N_NODES) return;
    int hl = lane & 31;   // lane within half
    int up = lane >> 5;   // which edge slot of the pair of halves
    int c0 = hl * 8;      // 8 columns per lane

    uint4 xru = *(const uint4*)(xr + (size_t)wid * FDIM + c0);
    f16x2 xr0 = u2h2(xru.x), xr1 = u2h2(xru.y), xr2 = u2h2(xru.z), xr3 = u2h2(xru.w);
    f32x4 av0 = *(const f32x4*)(att + c0);
    f32x4 av1 = *(const f32x4*)(att + c0 + 4);
    f16x2 a0 = {(_Float16)av0[0], (_Float16)av0[1]};
    f16x2 a1 = {(_Float16)av0[2], (_Float16)av0[3]};
    f16x2 a2 = {(_Float16)av1[0], (_Float16)av1[1]};
    f16x2 a3 = {(_Float16)av1[2], (_Float16)av1[3]};
    const f16x2 k02 = {(_Float16)0.2f, (_Float16)0.2f};

    f16x2 acc0 = {(_Float16)0.f, (_Float16)0.f};
    f16x2 acc1 = acc0, acc2 = acc0, acc3 = acc0;
    float den = 0.f;

    int jb = rowstart[wid], je = rowstart[wid + 1];
    if (jb < je) {
        int jlast = je - 1;
        int D = je - jb;
        int nsteps = (D + 3) >> 2;
        auto clamp = [&](int e) { return e > jlast ? jlast : e; };

        uint4 ua = *(const uint4*)(xl + (size_t)csr_src[clamp(jb + up)] * FDIM + c0);
        uint4 ub = *(const uint4*)(xl + (size_t)csr_src[clamp(jb + up + 2)] * FDIM + c0);

        for (int t = 0; t < nsteps; ++t) {
            int base = jb + 4 * t + up;
            uint4 na = *(const uint4*)(xl + (size_t)csr_src[clamp(base + 4)] * FDIM + c0);
            uint4 nb = *(const uint4*)(xl + (size_t)csr_src[clamp(base + 6)] * FDIM + c0);

            f16x2 xa0 = u2h2(ua.x), xa1 = u2h2(ua.y), xa2 = u2h2(ua.z), xa3 = u2h2(ua.w);
            f16x2 xb0 = u2h2(ub.x), xb1 = u2h2(ub.y), xb2 = u2h2(ub.z), xb3 = u2h2(ub.w);

            f16x2 va0 = xa0 + xr0, va1 = xa1 + xr1, va2 = xa2 + xr2, va3 = xa3 + xr3;
            f16x2 vb0 = xb0 + xr0, vb1 = xb1 + xr1, vb2 = xb2 + xr2, vb3 = xb3 + xr3;
            f16x2 ta0 = __builtin_elementwise_max(va0, va0 * k02);
            f16x2 tb0 = __builtin_elementwise_max(vb0, vb0 * k02);
            f16x2 ta1 = __builtin_elementwise_max(va1, va1 * k02);
            f16x2 tb1 = __builtin_elementwise_max(vb1, vb1 * k02);
            f16x2 ta2 = __builtin_elementwise_max(va2, va2 * k02);
            f16x2 tb2 = __builtin_elementwise_max(vb2, vb2 * k02);
            f16x2 ta3 = __builtin_elementwise_max(va3, va3 * k02);
            f16x2 tb3 = __builtin_elementwise_max(vb3, vb3 * k02);
            float sa = __builtin_amdgcn_fdot2(ta0, a0, 0.f, false);
            float sb = __builtin_amdgcn_fdot2(tb0, a0, 0.f, false);
            sa = __builtin_amdgcn_fdot2(ta1, a1, sa, false);
            sb = __builtin_amdgcn_fdot2(tb1, a1, sb, false);
            sa = __builtin_amdgcn_fdot2(ta2, a2, sa, false);
            sb = __builtin_amdgcn_fdot2(tb2, a2, sb, false);
            sa = __builtin_amdgcn_fdot2(ta3, a3, sa, false);
            sb = __builtin_amdgcn_fdot2(tb3, a3, sb, false);
            sa += __shfl_xor(sa, 1);
            sb += __shfl_xor(sb, 1);
            sa += __shfl_xor(sa, 2);
            sb += __shfl_xor(sb, 2);
            float ea = (base <= jlast) ? __expf(sa) : 0.f;
            float eb = (base + 2 <= jlast) ? __expf(sb) : 0.f;
            den += ea + eb;
            _Float16 eah = (_Float16)ea, ebh = (_Float16)eb;
            f16x2 eav = {eah, eah}, ebv = {ebh, ebh};
            acc0 += eav * xa0; acc0 += ebv * xb0;
            acc1 += eav * xa1; acc1 += ebv * xb1;
            acc2 += eav * xa2; acc2 += ebv * xb2;
            acc3 += eav * xa3; acc3 += ebv * xb3;
            ua = na; ub = nb;
        }
    }
    den += __shfl_xor(den, 32);
    acc0 += u2h2(__shfl_xor((int)h2u2(acc0), 32));
    acc1 += u2h2(__shfl_xor((int)h2u2(acc1), 32));
    acc2 += u2h2(__shfl_xor((int)h2u2(acc2), 32));
    acc3 += u2h2(__shfl_xor((int)h2u2(acc3), 32));

    if (up == 0) {
        float invf = 1.f / (den + 1e-16f);
        u16 h[8];
        h[0] = f2h((float)acc0[0] * invf); h[1] = f2h((float)acc0[1] * invf);
        h[2] = f2h((float)acc1[0] * invf); h[3] = f2h((float)acc1[1] * invf);
        h[4] = f2h((float)acc2[0] * invf); h[5] = f2h((float)acc2[1] * invf);
        h[6] = f2h((float)acc3[0] * invf); h[7] = f2h((float)acc3[1] * invf);
        *(uint4*)(out + (size_t)wid * FDIM + c0) = *(const uint4*)h;
    }
}

// ---------------- BatchNorm stats: proven column-per-thread layout,
// 4-deep grid-stride unroll (4 independent loads in flight per thread) ----------
__global__ void bn_stats_h(const u16* __restrict__ X, float* __restrict__ sum,
                           float* __restrict__ sumsq, int nrows) {
    int col = threadIdx.x;
    int stride = gridDim.x;
    float s = 0.f, ss = 0.f;
    int r = blockIdx.x;
    for (; r + 3 * stride < nrows; r += 4 * stride) {
        float v0 = h2f(X[(size_t)r * FDIM + col]);
        float v1 = h2f(X[(size_t)(r + stride) * FDIM + col]);
        float v2 = h2f(X[(size_t)(r + 2 * stride) * FDIM + col]);
        float v3 = h2f(X[(size_t)(r + 3 * stride) * FDIM + col]);
        s += v0 + v1 + v2 + v3;
        ss += v0 * v0 + v1 * v1 + v2 * v2 + v3 * v3;
    }
    for (; r < nrows; r += stride) {
        float v = h2f(X[(size_t)r * FDIM + col]);
        s += v;
        ss += v * v;
    }
    atomicAdd(&sum[col], s);
    atomicAdd(&sumsq[col], ss);
}

__global__ void bn_finalize(const float* __restrict__ sum, const float* __restrict__ sumsq,
                            const float* __restrict__ gamma, const float* __restrict__ beta,
                            float* __restrict__ scale, float* __restrict__ shift) {
    int c = threadIdx.x;
    float mean = sum[c] * (1.f / N_NODES);
    float var = sumsq[c] * (1.f / N_NODES) - mean * mean;
    float sc = gamma[c] * rsqrtf(var + 1e-5f);
    scale[c] = sc;
    shift[c] = beta[c] - mean * sc;
}

// BN + ELU fused: fp16 in, fp16 out (pad rows zeroed)
__global__ void bn_elu_h(const u16* __restrict__ X, const float* __restrict__ scale,
                         const float* __restrict__ shift, u16* __restrict__ dst) {
    int i = blockIdx.x * blockDim.x + threadIdx.x;   // ushort4 units
    int stride = gridDim.x * blockDim.x;
    const int n_valid4 = N_NODES * FDIM / 4;
    const int n_pad4 = NPAD * FDIM / 4;
    for (; i < n_pad4; i += stride) {
        u16 h[4] = {0, 0, 0, 0};
        if (i < n_valid4) {
            ushort4 v = ((const ushort4*)X)[i];
            int c0 = (i * 4) & (FDIM - 1);
            float f0 = h2f(v.x) * scale[c0 + 0] + shift[c0 + 0];
            float f1 = h2f(v.y) * scale[c0 + 1] + shift[c0 + 1];
            float f2 = h2f(v.z) * scale[c0 + 2] + shift[c0 + 2];
            float f3 = h2f(v.w) * scale[c0 + 3] + shift[c0 + 3];
            f0 = f0 > 0.f ? f0 : expf(f0) - 1.f;
            f1 = f1 > 0.f ? f1 : expf(f1) - 1.f;
            f2 = f2 > 0.f ? f2 : expf(f2) - 1.f;
            f3 = f3 > 0.f ? f3 : expf(f3) - 1.f;
            h[0] = f2h(f0); h[1] = f2h(f1); h[2] = f2h(f2); h[3] = f2h(f3);
        }
        ((ushort4*)dst)[i] = make_ushort4(h[0], h[1], h[2], h[3]);
    }
}

extern "C" void kernel_launch(void* const* d_in, const int* in_sizes, int n_in,
                              void* d_out, int out_size, void* d_ws, size_t ws_size,
                              hipStream_t stream) {
    const float* x     = (const float*)d_in[0];
    const int*   ei    = (const int*)d_in[1];
    const float* Wl1   = (const float*)d_in[2];
    const float* bl1   = (const float*)d_in[3];
    const float* Wr1   = (const float*)d_in[4];
    const float* br1   = (const float*)d_in[5];
    const float* att1  = (const float*)d_in[6];
    // d_in[7] = bias1 : cancels exactly inside batchnorm -> skipped
    const float* gamma1 = (const float*)d_in[8];
    const float* beta1  = (const float*)d_in[9];
    const float* Wl2   = (const float*)d_in[10];
    const float* bl2   = (const float*)d_in[11];
    const float* Wr2   = (const float*)d_in[12];
    const float* br2   = (const float*)d_in[13];
    const float* att2  = (const float*)d_in[14];
    // d_in[15] = bias2 : cancels inside batchnorm -> skipped
    const float* gamma2 = (const float*)d_in[16];
    const float* beta2  = (const float*)d_in[17];
    const float* Wfc   = (const float*)d_in[18];
    const float* bfc   = (const float*)d_in[19];

    const int* srcA = ei;
    const int* dstA = ei + N_EDGES;

    const size_t REG = (size_t)NPAD * FDIM * 4;
    char* p = (char*)d_ws;
    char* R0 = p;            p += REG;
    char* R1 = p;            p += REG;
    char* R2 = p;            p += REG;
    u16* WTH   = (u16*)p;              p += 512 * 256 * 2;
    float* SUM = (float*)p;            p += FDIM * 4;
    float* SQ  = (float*)p;            p += FDIM * 4;
    float* SC  = (float*)p;            p += FDIM * 4;
    float* SH  = (float*)p;            p += FDIM * 4;
    int* DEG      = (int*)p;           p += (size_t)N_NODES * 4;
    int* ROWSTART = (int*)p;           p += (size_t)(N_NODES + 1) * 4;
    int* CURSOR   = (int*)p;           p += (size_t)N_NODES * 4;
    int* CSR      = (int*)p;           p += (size_t)N_EDGES * 4;
    int* BLKSUM   = (int*)p;           p += (size_t)SCAN_NBLK * 4;

    const int gat_grid = (N_NODES + 3) / 4;   // one wave per node
    const int gemm_grid_layer = (NPAD / 128) * 4;  // 3128, 1D (swizzled in-kernel)
    const int gemm_grid_fc = NPAD / 128;           // 782

    // ---------------- CSR build ----------------
    hipMemsetAsync(DEG, 0, (size_t)N_NODES * sizeof(int), stream);
    count_deg<<<2048, 256, 0, stream>>>(dstA, DEG);
    scan_phase1<<<SCAN_NBLK, SCAN_BLOCK, 0, stream>>>(DEG, BLKSUM);
    scan_phase2<<<1, 512, 0, stream>>>(BLKSUM);
    scan_phase3<<<SCAN_NBLK, SCAN_BLOCK, 0, stream>>>(DEG, BLKSUM, ROWSTART, CURSOR);
    fill_csr<<<2048, 256, 0, stream>>>(srcA, dstA, CURSOR, CSR);

    // ---------------- Layer 1 ----------------
    // A(fp16) @ R0 ; gemm -> xl(fp16) @ R1, xr(fp16) @ R2 ; gat -> O(fp16) @ R0
    cast_half<<<4096, 256, 0, stream>>>(x, N_NODES * FDIM / 4, NPAD * FDIM / 4, (u16*)R0);
    prep_w_layer<<<512, 256, 0, stream>>>(Wl1, Wr1, WTH);
    gemm_h<true, 4, false><<<gemm_grid_layer, 512, 0, stream>>>((u16*)R0, WTH, bl1, br1, R1, R2, 256, N_NODES);
    gat_fused<<<gat_grid, 256, 0, stream>>>((u16*)R1, (u16*)R2, ROWSTART, CSR, att1, (u16*)R0);

    hipMemsetAsync(SUM, 0, 2 * FDIM * sizeof(float), stream);
    bn_stats_h<<<1024, 256, 0, stream>>>((u16*)R0, SUM, SQ, N_NODES);
    bn_finalize<<<1, 256, 0, stream>>>(SUM, SQ, gamma1, beta1, SC, SH);
    bn_elu_h<<<2048, 256, 0, stream>>>((u16*)R0, SC, SH, (u16*)R1);

    // ---------------- Layer 2 ----------------
    prep_w_layer<<<512, 256, 0, stream>>>(Wl2, Wr2, WTH);
    gemm_h<true, 4, false><<<gemm_grid_layer, 512, 0, stream>>>((u16*)R1, WTH, bl2, br2, R2, R0, 256, N_NODES);
    gat_fused<<<gat_grid, 256, 0, stream>>>((u16*)R2, (u16*)R0, ROWSTART, CSR, att2, (u16*)R1);

    hipMemsetAsync(SUM, 0, 2 * FDIM * sizeof(float), stream);
    bn_stats_h<<<1024, 256, 0, stream>>>((u16*)R1, SUM, SQ, N_NODES);
    bn_finalize<<<1, 256, 0, stream>>>(SUM, SQ, gamma2, beta2, SC, SH);
    bn_elu_h<<<2048, 256, 0, stream>>>((u16*)R1, SC, SH, (u16*)R2);

    // ---------------- FC with fused L2 normalize ----------------
    prep_w_fc<<<128, 256, 0, stream>>>(Wfc, WTH);
    gemm_h<false, 1, true><<<gemm_grid_fc, 512, 0, stream>>>((u16*)R2, WTH, bfc, bfc, d_out, d_out, 128, N_NODES);
}

// Round 25
// 555.126 us; speedup vs baseline: 1.2671x; 1.0092x over previous
//
#include <hip/hip_runtime.h>
#include <math.h>

#define N_NODES 100000
#define N_EDGES 800000
#define NPAD    100096   // 782 * 128
#define FDIM 256
#define HEADS 8
#define CDIM 32
#define OUTF 128

#define SCAN_BLOCK 256
#define SCAN_NBLK ((N_NODES + SCAN_BLOCK - 1) / SCAN_BLOCK)   // 391

typedef _Float16 f16x2 __attribute__((ext_vector_type(2)));
typedef _Float16 f16x8 __attribute__((ext_vector_type(8)));
typedef float  f32x4 __attribute__((ext_vector_type(4)));
typedef unsigned short u16;

__device__ __forceinline__ u16 f2h(float f) {
    union { _Float16 h; u16 u; } c;
    c.h = (_Float16)f;
    return c.u;
}
__device__ __forceinline__ float h2f(u16 u) {
    union { u16 u; _Float16 h; } c;
    c.u = u;
    return (float)c.h;
}
__device__ __forceinline__ f16x2 u2h2(unsigned u) {
    return __builtin_bit_cast(f16x2, u);
}
__device__ __forceinline__ unsigned h2u2(f16x2 h) {
    return __builtin_bit_cast(unsigned, h);
}

__device__ __forceinline__ void gload_lds16(const void* g, void* l) {
    __builtin_amdgcn_global_load_lds((const __attribute__((address_space(1))) void*)g,
                                     (__attribute__((address_space(3))) void*)l, 16, 0, 0);
}

// ---------------- cast f32 -> fp16 (pad region zeroed) ----------------
__global__ void cast_half(const float* __restrict__ src, int n_valid4, int n_pad4,
                          u16* __restrict__ dst) {
    int i = blockIdx.x * blockDim.x + threadIdx.x;
    int stride = gridDim.x * blockDim.x;
    for (; i < n_pad4; i += stride) {
        f32x4 v = {0.f, 0.f, 0.f, 0.f};
        if (i < n_valid4) v = ((const f32x4*)src)[i];
        ((ushort4*)dst)[i] = make_ushort4(f2h(v[0]), f2h(v[1]), f2h(v[2]), f2h(v[3]));
    }
}

// ---------------- W prep: transpose + concat, fp16 ----------------
__global__ void prep_w_layer(const float* __restrict__ Wl, const float* __restrict__ Wr,
                             u16* __restrict__ Wt) {
    int idx = blockIdx.x * blockDim.x + threadIdx.x;
    if (idx >= 512 * 256) return;
    int n = idx >> 8, k = idx & 255;
    float w = (n < 256) ? Wl[k * 256 + n] : Wr[k * 256 + (n - 256)];
    Wt[idx] = f2h(w);
}

__global__ void prep_w_fc(const float* __restrict__ Wfc, u16* __restrict__ Wt) {
    int idx = blockIdx.x * blockDim.x + threadIdx.x;
    if (idx >= 128 * 256) return;
    int n = idx >> 8, k = idx & 255;
    Wt[idx] = f2h(Wfc[k * 128 + n]);
}

// ---------------- fp16 MFMA GEMM, 2-phase dbuf LDS, 8 waves/block ----------------
template <bool HOUT, int NS, bool L2N>
__global__ __launch_bounds__(512) void gemm_h(
        const u16* __restrict__ A, const u16* __restrict__ Wt,
        const float* __restrict__ bias0, const float* __restrict__ bias1,
        void* __restrict__ C0v, void* __restrict__ C1v, int ldc, int M) {
    __shared__ __align__(16) u16 lA[2][128 * 64];
    __shared__ __align__(16) u16 lB[2][128 * 64];
    __shared__ float rssq[128];

    int tid = threadIdx.x;
    int wid = tid >> 6, lane = tid & 63;
    int wm = wid >> 1, wn = wid & 1;      // 4m x 2n wave grid
    int lr = lane & 15, lk = lane >> 4;

    // bijective XCD swizzle: consecutive swz ids stay on one XCD
    int orig = blockIdx.x;
    int nwg = gridDim.x;
    int q = nwg >> 3, r = nwg & 7;
    int xcd = orig & 7, loc = orig >> 3;
    int swz = (xcd < r) ? (xcd * (q + 1) + loc) : (r * (q + 1) + (xcd - r) * q + loc);
    int m0 = (swz / NS) * 128;
    int n0 = (swz % NS) * 128;

    auto stage = [&](int buf, int k0) {
#pragma unroll
        for (int i = 0; i < 2; i++) {
            int t = i * 512 + tid;
            int row = t >> 3;
            int ch = (t & 7) ^ (row & 7);
            gload_lds16(A + (size_t)(m0 + row) * 256 + k0 + ch * 8,
                        (char*)lA[buf] + i * 8192 + wid * 1024);
        }
#pragma unroll
        for (int i = 0; i < 2; i++) {
            int t = i * 512 + tid;
            int row = t >> 3;
            int ch = (t & 7) ^ (row & 7);
            gload_lds16(Wt + (size_t)(n0 + row) * 256 + k0 + ch * 8,
                        (char*)lB[buf] + i * 8192 + wid * 1024);
        }
    };

    f32x4 acc[2][4] = {};

    stage(0, 0);
    __syncthreads();

#pragma unroll 1
    for (int ks = 0; ks < 4; ks++) {
        int cur = ks & 1;
        if (ks < 3) stage(cur ^ 1, (ks + 1) * 64);

#pragma unroll
        for (int kk = 0; kk < 2; kk++) {
            f16x8 af[2], bf[4];
#pragma unroll
            for (int mr = 0; mr < 2; mr++) {
                int rr = wm * 32 + mr * 16 + lr;
                int qq = (kk * 4 + lk) ^ (rr & 7);
                af[mr] = *(const f16x8*)&lA[cur][rr * 64 + qq * 8];
            }
#pragma unroll
            for (int nr = 0; nr < 4; nr++) {
                int rr = wn * 64 + nr * 16 + lr;
                int qq = (kk * 4 + lk) ^ (rr & 7);
                bf[nr] = *(const f16x8*)&lB[cur][rr * 64 + qq * 8];
            }
#pragma unroll
            for (int mr = 0; mr < 2; mr++)
#pragma unroll
                for (int nr = 0; nr < 4; nr++)
                    acc[mr][nr] = __builtin_amdgcn_mfma_f32_16x16x32_f16(
                        af[mr], bf[nr], acc[mr][nr], 0, 0, 0);
        }
        __syncthreads();
    }

    // add bias in place
#pragma unroll
    for (int mr = 0; mr < 2; mr++)
#pragma unroll
        for (int nr = 0; nr < 4; nr++) {
            int col = n0 + wn * 64 + nr * 16 + lr;
            float b = (col < 256) ? bias0[col] : bias1[col - 256];
#pragma unroll
            for (int j = 0; j < 4; j++) acc[mr][nr][j] += b;
        }

    if constexpr (L2N) {
        if (tid < 128) rssq[tid] = 0.f;
        __syncthreads();
#pragma unroll
        for (int mr = 0; mr < 2; mr++)
#pragma unroll
            for (int j = 0; j < 4; j++) {
                int rl = wm * 32 + mr * 16 + lk * 4 + j;
                float s = 0.f;
#pragma unroll
                for (int nr = 0; nr < 4; nr++) s += acc[mr][nr][j] * acc[mr][nr][j];
                atomicAdd(&rssq[rl], s);
            }
        __syncthreads();
#pragma unroll
        for (int mr = 0; mr < 2; mr++)
#pragma unroll
            for (int j = 0; j < 4; j++) {
                int rl = wm * 32 + mr * 16 + lk * 4 + j;
                int row = m0 + rl;
                if (row < M) {
                    float inv = 1.f / fmaxf(sqrtf(rssq[rl]), 1e-12f);
#pragma unroll
                    for (int nr = 0; nr < 4; nr++) {
                        int col = n0 + wn * 64 + nr * 16 + lr;
                        ((float*)C0v)[(size_t)row * ldc + col] = acc[mr][nr][j] * inv;
                    }
                }
            }
    } else {
#pragma unroll
        for (int mr = 0; mr < 2; mr++)
#pragma unroll
            for (int nr = 0; nr < 4; nr++) {
                int col = n0 + wn * 64 + nr * 16 + lr;
                void* Cp; int c;
                if (col < 256) { Cp = C0v; c = col; }
                else           { Cp = C1v; c = col - 256; }
#pragma unroll
                for (int j = 0; j < 4; j++) {
                    int row = m0 + wm * 32 + mr * 16 + lk * 4 + j;
                    if (row < M) {
                        float v = acc[mr][nr][j];
                        if constexpr (HOUT)
                            ((u16*)Cp)[(size_t)row * ldc + c] = f2h(v);
                        else
                            ((float*)Cp)[(size_t)row * ldc + c] = v;
                    }
                }
            }
    }
}

// ---------------- CSR build ----------------
__global__ void count_deg(const int* __restrict__ dstA, int* __restrict__ deg) {
    int i = blockIdx.x * blockDim.x + threadIdx.x;
    int stride = gridDim.x * blockDim.x;
    for (; i < N_EDGES; i += stride) atomicAdd(&deg[dstA[i]], 1);
}

__global__ void scan_phase1(const int* __restrict__ deg, int* __restrict__ blocksum) {
    __shared__ int sdata[SCAN_BLOCK];
    int i = blockIdx.x * SCAN_BLOCK + threadIdx.x;
    sdata[threadIdx.x] = (i < N_NODES) ? deg[i] : 0;
    __syncthreads();
    for (int off = SCAN_BLOCK / 2; off > 0; off >>= 1) {
        if (threadIdx.x < off) sdata[threadIdx.x] += sdata[threadIdx.x + off];
        __syncthreads();
    }
    if (threadIdx.x == 0) blocksum[blockIdx.x] = sdata[0];
}

__global__ void scan_phase2(int* __restrict__ blocksum) {
    __shared__ int part[512];
    int t = threadIdx.x;
    int v = (t < SCAN_NBLK) ? blocksum[t] : 0;
    part[t] = v;
    __syncthreads();
    for (int off = 1; off < 512; off <<= 1) {
        int u = 0;
        if (t >= off) u = part[t - off];
        __syncthreads();
        if (t >= off) part[t] += u;
        __syncthreads();
    }
    if (t < SCAN_NBLK) blocksum[t] = part[t] - v;   // exclusive
}

__global__ void scan_phase3(const int* __restrict__ deg, const int* __restrict__ blockoff,
                            int* __restrict__ rowstart, int* __restrict__ cursor) {
    __shared__ int part[SCAN_BLOCK];
    int t = threadIdx.x;
    int i = blockIdx.x * SCAN_BLOCK + t;
    int v = (i < N_NODES) ? deg[i] : 0;
    part[t] = v;
    __syncthreads();
    for (int off = 1; off < SCAN_BLOCK; off <<= 1) {
        int u = 0;
        if (t >= off) u = part[t - off];
        __syncthreads();
        if (t >= off) part[t] += u;
        __syncthreads();
    }
    if (i < N_NODES) {
        int excl = blockoff[blockIdx.x] + part[t] - v;
        rowstart[i] = excl;
        cursor[i] = excl;
        if (i == N_NODES - 1) rowstart[N_NODES] = blockoff[blockIdx.x] + part[t];
    }
}

__global__ void fill_csr(const int* __restrict__ srcA, const int* __restrict__ dstA,
                         int* __restrict__ cursor, int* __restrict__ csr_src) {
    int i = blockIdx.x * blockDim.x + threadIdx.x;
    int stride = gridDim.x * blockDim.x;
    for (; i < N_EDGES; i += stride) {
        int pos = atomicAdd(&cursor[dstA[i]], 1);
        csr_src[pos] = srcA[i];
    }
}

// ---------------- Fused GATv2 edge phase (one wave per destination) ----------------
// Two 32-lane halves; each half processes FOUR independent edges per iteration
// (offsets 8t+up+2k, k=0..3): 4 logit chains interleave; 8 gather streams in flight.
__global__ void gat_fused(const u16* __restrict__ xl, const u16* __restrict__ xr,
                          const int* __restrict__ rowstart, const int* __restrict__ csr_src,
                          const float* __restrict__ att, u16* __restrict__ out) {
    int wid = (blockIdx.x * blockDim.x + threadIdx.x) >> 6;
    int lane = threadIdx.x & 63;
    if (wid >= N_NODES) return;
    int hl = lane & 31;   // lane within half
    int up = lane >> 5;   // edge slot parity
    int c0 = hl * 8;      // 8 columns per lane

    uint4 xru = *(const uint4*)(xr + (size_t)wid * FDIM + c0);
    f16x2 xr0 = u2h2(xru.x), xr1 = u2h2(xru.y), xr2 = u2h2(xru.z), xr3 = u2h2(xru.w);
    f32x4 av0 = *(const f32x4*)(att + c0);
    f32x4 av1 = *(const f32x4*)(att + c0 + 4);
    f16x2 a0 = {(_Float16)av0[0], (_Float16)av0[1]};
    f16x2 a1 = {(_Float16)av0[2], (_Float16)av0[3]};
    f16x2 a2 = {(_Float16)av1[0], (_Float16)av1[1]};
    f16x2 a3 = {(_Float16)av1[2], (_Float16)av1[3]};
    const f16x2 k02 = {(_Float16)0.2f, (_Float16)0.2f};

    f16x2 acc0 = {(_Float16)0.f, (_Float16)0.f};
    f16x2 acc1 = acc0, acc2 = acc0, acc3 = acc0;
    float den = 0.f;

    int jb = rowstart[wid], je = rowstart[wid + 1];
    if (jb < je) {
        int jlast = je - 1;
        int D = je - jb;
        int nsteps = (D + 7) >> 3;   // each iter: this half covers 8t+up+{0,2,4,6}
        auto clamp = [&](int e) { return e > jlast ? jlast : e; };

        uint4 u[4], n[4];
#pragma unroll
        for (int k = 0; k < 4; k++)
            u[k] = *(const uint4*)(xl + (size_t)csr_src[clamp(jb + up + 2 * k)] * FDIM + c0);

        for (int t = 0; t < nsteps; ++t) {
            int base = jb + 8 * t + up;
#pragma unroll
            for (int k = 0; k < 4; k++)
                n[k] = *(const uint4*)(xl + (size_t)csr_src[clamp(base + 8 + 2 * k)] * FDIM + c0);

#pragma unroll
            for (int k = 0; k < 4; k++) {
                f16x2 x0 = u2h2(u[k].x), x1 = u2h2(u[k].y);
                f16x2 x2 = u2h2(u[k].z), x3 = u2h2(u[k].w);
                f16x2 v0 = x0 + xr0, v1 = x1 + xr1, v2 = x2 + xr2, v3 = x3 + xr3;
                f16x2 t0 = __builtin_elementwise_max(v0, v0 * k02);
                f16x2 t1 = __builtin_elementwise_max(v1, v1 * k02);
                f16x2 t2 = __builtin_elementwise_max(v2, v2 * k02);
                f16x2 t3 = __builtin_elementwise_max(v3, v3 * k02);
                float s = __builtin_amdgcn_fdot2(t0, a0, 0.f, false);
                s = __builtin_amdgcn_fdot2(t1, a1, s, false);
                s = __builtin_amdgcn_fdot2(t2, a2, s, false);
                s = __builtin_amdgcn_fdot2(t3, a3, s, false);
                s += __shfl_xor(s, 1);
                s += __shfl_xor(s, 2);
                float e = (base + 2 * k <= jlast) ? __expf(s) : 0.f;
                den += e;
                _Float16 eh = (_Float16)e;
                f16x2 ev = {eh, eh};
                acc0 += ev * x0;
                acc1 += ev * x1;
                acc2 += ev * x2;
                acc3 += ev * x3;
            }
#pragma unroll
            for (int k = 0; k < 4; k++) u[k] = n[k];
        }
    }
    // merge the two halves (same columns, disjoint edge sets)
    den += __shfl_xor(den, 32);
    acc0 += u2h2(__shfl_xor((int)h2u2(acc0), 32));
    acc1 += u2h2(__shfl_xor((int)h2u2(acc1), 32));
    acc2 += u2h2(__shfl_xor((int)h2u2(acc2), 32));
    acc3 += u2h2(__shfl_xor((int)h2u2(acc3), 32));

    if (up == 0) {
        float invf = 1.f / (den + 1e-16f);
        u16 h[8];
        h[0] = f2h((float)acc0[0] * invf); h[1] = f2h((float)acc0[1] * invf);
        h[2] = f2h((float)acc1[0] * invf); h[3] = f2h((float)acc1[1] * invf);
        h[4] = f2h((float)acc2[0] * invf); h[5] = f2h((float)acc2[1] * invf);
        h[6] = f2h((float)acc3[0] * invf); h[7] = f2h((float)acc3[1] * invf);
        *(uint4*)(out + (size_t)wid * FDIM + c0) = *(const uint4*)h;
    }
}

// ---------------- BatchNorm stats: column-per-thread, 4-deep unroll ----------------
__global__ void bn_stats_h(const u16* __restrict__ X, float* __restrict__ sum,
                           float* __restrict__ sumsq, int nrows) {
    int col = threadIdx.x;
    int stride = gridDim.x;
    float s = 0.f, ss = 0.f;
    int r = blockIdx.x;
    for (; r + 3 * stride < nrows; r += 4 * stride) {
        float v0 = h2f(X[(size_t)r * FDIM + col]);
        float v1 = h2f(X[(size_t)(r + stride) * FDIM + col]);
        float v2 = h2f(X[(size_t)(r + 2 * stride) * FDIM + col]);
        float v3 = h2f(X[(size_t)(r + 3 * stride) * FDIM + col]);
        s += v0 + v1 + v2 + v3;
        ss += v0 * v0 + v1 * v1 + v2 * v2 + v3 * v3;
    }
    for (; r < nrows; r += stride) {
        float v = h2f(X[(size_t)r * FDIM + col]);
        s += v;
        ss += v * v;
    }
    atomicAdd(&sum[col], s);
    atomicAdd(&sumsq[col], ss);
}

__global__ void bn_finalize(const float* __restrict__ sum, const float* __restrict__ sumsq,
                            const float* __restrict__ gamma, const float* __restrict__ beta,
                            float* __restrict__ scale, float* __restrict__ shift) {
    int c = threadIdx.x;
    float mean = sum[c] * (1.f / N_NODES);
    float var = sumsq[c] * (1.f / N_NODES) - mean * mean;
    float sc = gamma[c] * rsqrtf(var + 1e-5f);
    scale[c] = sc;
    shift[c] = beta[c] - mean * sc;
}

// BN + ELU fused: fp16 in, fp16 out (pad rows zeroed)
__global__ void bn_elu_h(const u16* __restrict__ X, const float* __restrict__ scale,
                         const float* __restrict__ shift, u16* __restrict__ dst) {
    int i = blockIdx.x * blockDim.x + threadIdx.x;   // ushort4 units
    int stride = gridDim.x * blockDim.x;
    const int n_valid4 = N_NODES * FDIM / 4;
    const int n_pad4 = NPAD * FDIM / 4;
    for (; i < n_pad4; i += stride) {
        u16 h[4] = {0, 0, 0, 0};
        if (i < n_valid4) {
            ushort4 v = ((const ushort4*)X)[i];
            int c0 = (i * 4) & (FDIM - 1);
            float f0 = h2f(v.x) * scale[c0 + 0] + shift[c0 + 0];
            float f1 = h2f(v.y) * scale[c0 + 1] + shift[c0 + 1];
            float f2 = h2f(v.z) * scale[c0 + 2] + shift[c0 + 2];
            float f3 = h2f(v.w) * scale[c0 + 3] + shift[c0 + 3];
            f0 = f0 > 0.f ? f0 : expf(f0) - 1.f;
            f1 = f1 > 0.f ? f1 : expf(f1) - 1.f;
            f2 = f2 > 0.f ? f2 : expf(f2) - 1.f;
            f3 = f3 > 0.f ? f3 : expf(f3) - 1.f;
            h[0] = f2h(f0); h[1] = f2h(f1); h[2] = f2h(f2); h[3] = f2h(f3);
        }
        ((ushort4*)dst)[i] = make_ushort4(h[0], h[1], h[2], h[3]);
    }
}

extern "C" void kernel_launch(void* const* d_in, const int* in_sizes, int n_in,
                              void* d_out, int out_size, void* d_ws, size_t ws_size,
                              hipStream_t stream) {
    const float* x     = (const float*)d_in[0];
    const int*   ei    = (const int*)d_in[1];
    const float* Wl1   = (const float*)d_in[2];
    const float* bl1   = (const float*)d_in[3];
    const float* Wr1   = (const float*)d_in[4];
    const float* br1   = (const float*)d_in[5];
    const float* att1  = (const float*)d_in[6];
    // d_in[7] = bias1 : cancels exactly inside batchnorm -> skipped
    const float* gamma1 = (const float*)d_in[8];
    const float* beta1  = (const float*)d_in[9];
    const float* Wl2   = (const float*)d_in[10];
    const float* bl2   = (const float*)d_in[11];
    const float* Wr2   = (const float*)d_in[12];
    const float* br2   = (const float*)d_in[13];
    const float* att2  = (const float*)d_in[14];
    // d_in[15] = bias2 : cancels inside batchnorm -> skipped
    const float* gamma2 = (const float*)d_in[16];
    const float* beta2  = (const float*)d_in[17];
    const float* Wfc   = (const float*)d_in[18];
    const float* bfc   = (const float*)d_in[19];

    const int* srcA = ei;
    const int* dstA = ei + N_EDGES;

    const size_t REG = (size_t)NPAD * FDIM * 4;
    char* p = (char*)d_ws;
    char* R0 = p;            p += REG;
    char* R1 = p;            p += REG;
    char* R2 = p;            p += REG;
    u16* WTH   = (u16*)p;              p += 512 * 256 * 2;
    float* SUM = (float*)p;            p += FDIM * 4;
    float* SQ  = (float*)p;            p += FDIM * 4;
    float* SC  = (float*)p;            p += FDIM * 4;
    float* SH  = (float*)p;            p += FDIM * 4;
    int* DEG      = (int*)p;           p += (size_t)N_NODES * 4;
    int* ROWSTART = (int*)p;           p += (size_t)(N_NODES + 1) * 4;
    int* CURSOR   = (int*)p;           p += (size_t)N_NODES * 4;
    int* CSR      = (int*)p;           p += (size_t)N_EDGES * 4;
    int* BLKSUM   = (int*)p;           p += (size_t)SCAN_NBLK * 4;

    const int gat_grid = (N_NODES + 3) / 4;   // one wave per node
    const int gemm_grid_layer = (NPAD / 128) * 4;  // 3128, 1D (swizzled in-kernel)
    const int gemm_grid_fc = NPAD / 128;           // 782

    // ---------------- CSR build ----------------
    hipMemsetAsync(DEG, 0, (size_t)N_NODES * sizeof(int), stream);
    count_deg<<<2048, 256, 0, stream>>>(dstA, DEG);
    scan_phase1<<<SCAN_NBLK, SCAN_BLOCK, 0, stream>>>(DEG, BLKSUM);
    scan_phase2<<<1, 512, 0, stream>>>(BLKSUM);
    scan_phase3<<<SCAN_NBLK, SCAN_BLOCK, 0, stream>>>(DEG, BLKSUM, ROWSTART, CURSOR);
    fill_csr<<<2048, 256, 0, stream>>>(srcA, dstA, CURSOR, CSR);

    // ---------------- Layer 1 ----------------
    // A(fp16) @ R0 ; gemm -> xl(fp16) @ R1, xr(fp16) @ R2 ; gat -> O(fp16) @ R0
    cast_half<<<4096, 256, 0, stream>>>(x, N_NODES * FDIM / 4, NPAD * FDIM / 4, (u16*)R0);
    prep_w_layer<<<512, 256, 0, stream>>>(Wl1, Wr1, WTH);
    gemm_h<true, 4, false><<<gemm_grid_layer, 512, 0, stream>>>((u16*)R0, WTH, bl1, br1, R1, R2, 256, N_NODES);
    gat_fused<<<gat_grid, 256, 0, stream>>>((u16*)R1, (u16*)R2, ROWSTART, CSR, att1, (u16*)R0);

    hipMemsetAsync(SUM, 0, 2 * FDIM * sizeof(float), stream);
    bn_stats_h<<<1024, 256, 0, stream>>>((u16*)R0, SUM, SQ, N_NODES);
    bn_finalize<<<1, 256, 0, stream>>>(SUM, SQ, gamma1, beta1, SC, SH);
    bn_elu_h<<<2048, 256, 0, stream>>>((u16*)R0, SC, SH, (u16*)R1);

    // ---------------- Layer 2 ----------------
    prep_w_layer<<<512, 256, 0, stream>>>(Wl2, Wr2, WTH);
    gemm_h<true, 4, false><<<gemm_grid_layer, 512, 0, stream>>>((u16*)R1, WTH, bl2, br2, R2, R0, 256, N_NODES);
    gat_fused<<<gat_grid, 256, 0, stream>>>((u16*)R2, (u16*)R0, ROWSTART, CSR, att2, (u16*)R1);

    hipMemsetAsync(SUM, 0, 2 * FDIM * sizeof(float), stream);
    bn_stats_h<<<1024, 256, 0, stream>>>((u16*)R1, SUM, SQ, N_NODES);
    bn_finalize<<<1, 256, 0, stream>>>(SUM, SQ, gamma2, beta2, SC, SH);
    bn_elu_h<<<2048, 256, 0, stream>>>((u16*)R1, SC, SH, (u16*)R2);

    // ---------------- FC with fused L2 normalize ----------------
    prep_w_fc<<<128, 256, 0, stream>>>(Wfc, WTH);
    gemm_h<false, 1, true><<<gemm_grid_fc, 512, 0, stream>>>((u16*)R2, WTH, bfc, bfc, d_out, d_out, 128, N_NODES);
}